// Round 1
// baseline (734.725 us; speedup 1.0000x reference)
//
#include <hip/hip_runtime.h>

// SatelliteCBF V_with_jacobian, MI355X fp32.
//
// Algorithm: backward (VJP) Jacobian accumulation instead of the reference's
// forward 128x6 propagation: 131K MAC/sample vs 465K. Output dim is 1, so
//   J = w_out*W3*D3*W2*D2*W1*D1*W0*D0*W_in*diag(1/r)
// is evaluated right-to-left as vec-mat products with elementwise D scaling.
//
// Mapping: lane <-> sample (64 samples/block), 4 waves/block, each wave owns a
// wave-UNIFORM 32-wide h (or k) output slice -> weight indices are uniform ->
// compiler emits s_load + v_fmac with SGPR operand (weights never touch
// LDS/VMEM per-MAC). Activations A0..A3 live in 4 LDS buffers; each lane only
// ever touches its OWN row (cross-wave sharing is column-split, barrier
// separated). Backward g-vectors overwrite the A-buffers in place (per-wave
// k-ranges are disjoint -> race-free).
//
// LDS: 4*64*132*4 + u(128) + vpart(256) = 136704 B dynamic -> 1 block/CU.

#define N_DIMS 6
#define HID    128
#define BS     65536
#define SPB    64     // samples per block (lane <-> sample)
#define NW     4      // waves per block
#define STRIDE 132    // padded LDS row stride (floats); 132*4 % 16 == 0 for b128

__device__ __forceinline__ float fast_tanh(float x) {
  // tanh(x) = 1 - 2/(e^{2x}+1); graceful at +-inf. ~5 VALU ops.
  float e = __expf(2.0f * x);
  return 1.0f - 2.0f * __builtin_amdgcn_rcpf(e + 1.0f);
}

__global__ __launch_bounds__(256, 1)
void cbf_fused(const float* __restrict__ x,
               const float* __restrict__ xc,
               const float* __restrict__ xr,
               const float* __restrict__ w_in,
               const float* __restrict__ b_in,
               const float* __restrict__ w_h,
               const float* __restrict__ b_h,
               const float* __restrict__ w_out,
               const float* __restrict__ b_out,
               float* __restrict__ out)
{
  extern __shared__ float smem[];
  float* buf0  = smem;                    // A0 -> g0
  float* buf1  = buf0 + SPB * STRIDE;     // A1 -> g1
  float* buf2  = buf1 + SPB * STRIDE;     // A2 -> g2
  float* buf3  = buf2 + SPB * STRIDE;     // A3 (read-only in bwd)
  float* ubuf  = buf3 + SPB * STRIDE;     // u = w_out @ w_h[3]   [128]
  float* vpart = ubuf + HID;              // per-wave V partials  [NW][SPB]

  const int tid  = threadIdx.x;
  const int lane = tid & 63;
  // readfirstlane -> compiler KNOWS wave id is uniform -> h = hb+hl is uniform
  // -> weight loads scalarize (s_load + v_fmac with SGPR operand).
  const int wid  = __builtin_amdgcn_readfirstlane(tid >> 6);
  const int hb   = wid * 32;
  const int gs   = blockIdx.x * SPB + lane;

  // ---- u = w_out @ w_h[3]  (sample-independent; cooperative, coalesced) ----
  if (tid < HID) {
    const float* w3 = w_h + 3 * HID * HID;
    float acc = 0.f;
    #pragma unroll 4
    for (int h = 0; h < HID; ++h)
      acc = fmaf(w_out[h], w3[h * HID + tid], acc);
    ubuf[tid] = acc;
  }

  // ---- P0: xn, A0 = tanh(W_in xn + b_in) ----
  float xn[N_DIMS];
  #pragma unroll
  for (int d = 0; d < N_DIMS; ++d)
    xn[d] = (x[gs * N_DIMS + d] - xc[d]) / xr[d];

  {
    float* row = buf0 + lane * STRIDE;
    #pragma unroll 2
    for (int hl = 0; hl < 32; ++hl) {
      const int h = hb + hl;
      float a = b_in[h];
      #pragma unroll
      for (int d = 0; d < N_DIMS; ++d)
        a = fmaf(w_in[h * N_DIMS + d], xn[d], a);
      row[h] = fast_tanh(a);
    }
  }
  __syncthreads();

  // ---- P1..P3: A_{L+1} = tanh(W_L A_L + b_L), L = 0..2 ----
  for (int L = 0; L < 3; ++L) {
    const float* bin  = smem + L * SPB * STRIDE + lane * STRIDE;
    float*       bout = smem + (L + 1) * SPB * STRIDE + lane * STRIDE;
    const float* wp   = w_h + L * HID * HID;
    const float* bp   = b_h + L * HID;

    float a[HID];                       // own activation row -> VGPRs (static idx)
    #pragma unroll
    for (int kq = 0; kq < HID; kq += 4) {
      float4 t = *(const float4*)(bin + kq);
      a[kq] = t.x; a[kq + 1] = t.y; a[kq + 2] = t.z; a[kq + 3] = t.w;
    }
    #pragma unroll 2
    for (int hl = 0; hl < 32; ++hl) {
      const int h = hb + hl;
      const float* wr = wp + h * HID;   // uniform -> s_load_dwordx4 stream
      float p0 = bp[h], p1 = 0.f, p2 = 0.f, p3 = 0.f;
      #pragma unroll
      for (int k = 0; k < HID; k += 4) {
        p0 = fmaf(wr[k + 0], a[k + 0], p0);
        p1 = fmaf(wr[k + 1], a[k + 1], p1);
        p2 = fmaf(wr[k + 2], a[k + 2], p2);
        p3 = fmaf(wr[k + 3], a[k + 3], p3);
      }
      bout[h] = fast_tanh((p0 + p1) + (p2 + p3));
    }
    __syncthreads();
  }

  // ---- P4: A4 = W3 A3 + b3 (no tanh), folded into V = w_out.A4 + b_out ----
  {
    const float* bin = buf3 + lane * STRIDE;
    const float* wp  = w_h + 3 * HID * HID;
    const float* bp  = b_h + 3 * HID;
    float a[HID];
    #pragma unroll
    for (int kq = 0; kq < HID; kq += 4) {
      float4 t = *(const float4*)(bin + kq);
      a[kq] = t.x; a[kq + 1] = t.y; a[kq + 2] = t.z; a[kq + 3] = t.w;
    }
    float vacc = 0.f;
    #pragma unroll 2
    for (int hl = 0; hl < 32; ++hl) {
      const int h = hb + hl;
      const float* wr = wp + h * HID;
      float p0 = bp[h], p1 = 0.f, p2 = 0.f, p3 = 0.f;
      #pragma unroll
      for (int k = 0; k < HID; k += 4) {
        p0 = fmaf(wr[k + 0], a[k + 0], p0);
        p1 = fmaf(wr[k + 1], a[k + 1], p1);
        p2 = fmaf(wr[k + 2], a[k + 2], p2);
        p3 = fmaf(wr[k + 3], a[k + 3], p3);
      }
      vacc = fmaf(w_out[h], (p0 + p1) + (p2 + p3), vacc);
    }
    vpart[wid * SPB + lane] = vacc;
  }
  __syncthreads();

  if (wid == 0)
    out[gs] = vpart[lane] + vpart[SPB + lane] + vpart[2 * SPB + lane]
            + vpart[3 * SPB + lane] + b_out[0];

  // ---- P5..P7: backward  g_{BL} = (g_{BL+1}^T W_BL) * (1 - A_BL^2) ----
  // BL==2: g3 = u * (1 - A3^2) built on the fly from buf3.
  for (int BL = 2; BL >= 0; --BL) {
    const float* gin = smem + (BL + 1) * SPB * STRIDE + lane * STRIDE;
    float g[HID];
    if (BL == 2) {
      #pragma unroll
      for (int kq = 0; kq < HID; kq += 4) {
        float4 t  = *(const float4*)(gin + kq);
        float4 uu = *(const float4*)(ubuf + kq);   // uniform addr -> broadcast
        g[kq + 0] = uu.x * (1.f - t.x * t.x);
        g[kq + 1] = uu.y * (1.f - t.y * t.y);
        g[kq + 2] = uu.z * (1.f - t.z * t.z);
        g[kq + 3] = uu.w * (1.f - t.w * t.w);
      }
    } else {
      #pragma unroll
      for (int kq = 0; kq < HID; kq += 4) {
        float4 t = *(const float4*)(gin + kq);
        g[kq] = t.x; g[kq + 1] = t.y; g[kq + 2] = t.z; g[kq + 3] = t.w;
      }
    }
    const float* wp   = w_h + BL * HID * HID;
    float*       drow = smem + BL * SPB * STRIDE + lane * STRIDE; // A_BL in, g_BL out
    #pragma unroll 1
    for (int kl = 0; kl < 32; kl += 4) {
      const int k = hb + kl;            // uniform k-range per wave
      float q0 = 0.f, q1 = 0.f, q2 = 0.f, q3 = 0.f;
      #pragma unroll
      for (int h = 0; h < HID; ++h) {
        const float gh = g[h];
        q0 = fmaf(wp[h * HID + k + 0], gh, q0);   // s_load_dwordx4, K$-resident
        q1 = fmaf(wp[h * HID + k + 1], gh, q1);
        q2 = fmaf(wp[h * HID + k + 2], gh, q2);
        q3 = fmaf(wp[h * HID + k + 3], gh, q3);
      }
      const float a0 = drow[k + 0], a1 = drow[k + 1];
      const float a2 = drow[k + 2], a3 = drow[k + 3];
      drow[k + 0] = q0 * (1.f - a0 * a0);
      drow[k + 1] = q1 * (1.f - a1 * a1);
      drow[k + 2] = q2 * (1.f - a2 * a2);
      drow[k + 3] = q3 * (1.f - a3 * a3);
    }
    __syncthreads();
  }

  // ---- P8: J[n] = (sum_k g0[k] * w_in[k,n]) / r[n] ----
  if (wid == 0) {
    const float* g0 = buf0 + lane * STRIDE;
    float J[N_DIMS] = {0.f, 0.f, 0.f, 0.f, 0.f, 0.f};
    #pragma unroll 4
    for (int k = 0; k < HID; ++k) {
      const float gk = g0[k];
      #pragma unroll
      for (int n = 0; n < N_DIMS; ++n)
        J[n] = fmaf(w_in[k * N_DIMS + n], gk, J[n]);
    }
    #pragma unroll
    for (int n = 0; n < N_DIMS; ++n)
      out[BS + gs * N_DIMS + n] = J[n] / xr[n];
  }
}

extern "C" void kernel_launch(void* const* d_in, const int* in_sizes, int n_in,
                              void* d_out, int out_size, void* d_ws, size_t ws_size,
                              hipStream_t stream) {
  const float* x     = (const float*)d_in[0];
  const float* xc    = (const float*)d_in[1];
  const float* xr    = (const float*)d_in[2];
  const float* w_in  = (const float*)d_in[3];
  const float* b_in  = (const float*)d_in[4];
  const float* w_h   = (const float*)d_in[5];
  const float* b_h   = (const float*)d_in[6];
  const float* w_out = (const float*)d_in[7];
  const float* b_out = (const float*)d_in[8];
  float* out = (float*)d_out;

  const size_t shmem = (size_t)(4 * SPB * STRIDE + HID + NW * SPB) * sizeof(float);
  // >64KB dynamic LDS: opt-in attribute (idempotent host call; capture-safe).
  (void)hipFuncSetAttribute((const void*)cbf_fused,
                            hipFuncAttributeMaxDynamicSharedMemorySize,
                            (int)shmem);
  cbf_fused<<<dim3(BS / SPB), dim3(256), shmem, stream>>>(
      x, xc, xr, w_in, b_in, w_h, b_h, w_out, b_out, out);
}

// Round 2
// 350.856 us; speedup vs baseline: 2.0941x; 2.0941x over previous
//
#include <hip/hip_runtime.h>

// SatelliteCBF V_with_jacobian, MI355X fp32 — round 2.
//
// VJP (backward) Jacobian: J = w_out*W3*D3*...*D0*W_in*diag(1/r) evaluated
// right-to-left, ~116K FMA/sample vs reference's 465K.
//
// R1 post-mortem: 724us, VALUBusy 17%, occupancy 11.7% -> latency-bound at
// 1 wave/SIMD. This round: same 64-samples/block LDS plan (2KB/sample is
// forced by storing A0..A3 for backward), but 16 waves/block (1024 thr),
// each wave owning an 8-wide h/k slice -> 4 waves/SIMD. Register use kept
// <=128 by chunked-k activation caching (8 floats from LDS reused across the
// wave's 8 rows; FMA:LDS = 8:1). Weights scalarize (wave-uniform h/k slice +
// readfirstlane'd wid) -> s_load + v_fmac with SGPR operand.
//
// LDS layout: XOR-swizzled 16B granules: granule g of row r lives at
// r*32 + (g ^ (r&31)) -> b128 reads across 64 rows hit every bank group
// uniformly (structural minimum), no padding needed, b128 alignment kept.
//
// Phases (barrier between each): P0 in-layer | P1..P3 hidden fwd | P4 V
// partials | P4b g3 = D3*(W3^T w_out) | P5..P7 g_{L} bwd (in-place over A_L)
// | P8 wave0: V sum + J = (g0^T W_in)/r.

#define N_DIMS 6
#define HID    128
#define BS     65536
#define SPB    64     // samples per block (lane <-> sample)
#define NW     16     // waves per block
#define RPW    8      // h/k rows per wave

__device__ __forceinline__ float fast_tanh(float x) {
  float e = __expf(2.0f * x);
  return 1.0f - 2.0f * __builtin_amdgcn_rcpf(e + 1.0f);
}

// float offset of 16B granule g (0..31) of row r in a [64][128] f32 buffer
__device__ __forceinline__ int swz(int r, int g) {
  return ((r << 5) + (g ^ (r & 31))) << 2;
}

__device__ __forceinline__ void load8(const float* __restrict__ buf, int r, int c,
                                      float* __restrict__ v) {
  const float4 t0 = *(const float4*)(buf + swz(r, 2 * c));
  const float4 t1 = *(const float4*)(buf + swz(r, 2 * c + 1));
  v[0] = t0.x; v[1] = t0.y; v[2] = t0.z; v[3] = t0.w;
  v[4] = t1.x; v[5] = t1.y; v[6] = t1.z; v[7] = t1.w;
}

__device__ __forceinline__ void store8(float* __restrict__ buf, int r, int c,
                                       const float* __restrict__ v) {
  *(float4*)(buf + swz(r, 2 * c))     = make_float4(v[0], v[1], v[2], v[3]);
  *(float4*)(buf + swz(r, 2 * c + 1)) = make_float4(v[4], v[5], v[6], v[7]);
}

__global__ __launch_bounds__(1024, 4)
void cbf_fused(const float* __restrict__ x,
               const float* __restrict__ xc,
               const float* __restrict__ xr,
               const float* __restrict__ w_in,
               const float* __restrict__ b_in,
               const float* __restrict__ w_h,
               const float* __restrict__ b_h,
               const float* __restrict__ w_out,
               const float* __restrict__ b_out,
               float* __restrict__ out)
{
  extern __shared__ float smem[];            // buf0..buf3: 4 x [64][128]
  float* vpart = smem + 4 * SPB * HID;       // [NW][64] V partials

  const int tid  = threadIdx.x;
  const int lane = tid & 63;
  const int wid  = __builtin_amdgcn_readfirstlane(tid >> 6);
  const int hb   = wid * RPW;                // wave's uniform h/k slice base
  const int gs   = blockIdx.x * SPB + lane;

  // ---- P0: xn, A0 = tanh(W_in xn + b_in), wave's 8-row h slice ----
  float xn[N_DIMS];
  {
    const float2* xp = (const float2*)(x + gs * N_DIMS);
    const float2 x0 = xp[0], x1 = xp[1], x2 = xp[2];
    xn[0] = (x0.x - xc[0]) / xr[0];
    xn[1] = (x0.y - xc[1]) / xr[1];
    xn[2] = (x1.x - xc[2]) / xr[2];
    xn[3] = (x1.y - xc[3]) / xr[3];
    xn[4] = (x2.x - xc[4]) / xr[4];
    xn[5] = (x2.y - xc[5]) / xr[5];
  }
  {
    float acc[RPW];
    #pragma unroll
    for (int r = 0; r < RPW; ++r) {
      float a = b_in[hb + r];
      #pragma unroll
      for (int d = 0; d < N_DIMS; ++d)
        a = fmaf(w_in[(hb + r) * N_DIMS + d], xn[d], a);
      acc[r] = fast_tanh(a);
    }
    store8(smem, lane, wid, acc);
  }
  __syncthreads();

  // ---- P1..P3: A_{L+1} = tanh(W_L A_L + b_L) ----
  for (int L = 0; L < 3; ++L) {
    const float* bin  = smem + L * SPB * HID;
    float*       bout = smem + (L + 1) * SPB * HID;
    const float* wp   = w_h + L * HID * HID;
    float acc[RPW];
    #pragma unroll
    for (int r = 0; r < RPW; ++r) acc[r] = b_h[L * HID + hb + r];
    #pragma unroll
    for (int c = 0; c < 16; ++c) {           // 8-float k chunks
      float ac[8];
      load8(bin, lane, c, ac);
      #pragma unroll
      for (int r = 0; r < RPW; ++r) {
        const float* wr = wp + (hb + r) * HID + c * 8;  // uniform -> s_load
        float a = acc[r];
        a = fmaf(wr[0], ac[0], a); a = fmaf(wr[1], ac[1], a);
        a = fmaf(wr[2], ac[2], a); a = fmaf(wr[3], ac[3], a);
        a = fmaf(wr[4], ac[4], a); a = fmaf(wr[5], ac[5], a);
        a = fmaf(wr[6], ac[6], a); a = fmaf(wr[7], ac[7], a);
        acc[r] = a;
      }
    }
    #pragma unroll
    for (int r = 0; r < RPW; ++r) acc[r] = fast_tanh(acc[r]);
    store8(bout, lane, wid, acc);
    __syncthreads();
  }

  // ---- P4: V partials: vacc = sum_{h in slice} w_out[h]*(W3 A3 + b3)[h] ----
  {
    const float* bin = smem + 3 * SPB * HID;
    const float* wp  = w_h + 3 * HID * HID;
    float acc[RPW];
    #pragma unroll
    for (int r = 0; r < RPW; ++r) acc[r] = b_h[3 * HID + hb + r];
    #pragma unroll
    for (int c = 0; c < 16; ++c) {
      float ac[8];
      load8(bin, lane, c, ac);
      #pragma unroll
      for (int r = 0; r < RPW; ++r) {
        const float* wr = wp + (hb + r) * HID + c * 8;
        float a = acc[r];
        a = fmaf(wr[0], ac[0], a); a = fmaf(wr[1], ac[1], a);
        a = fmaf(wr[2], ac[2], a); a = fmaf(wr[3], ac[3], a);
        a = fmaf(wr[4], ac[4], a); a = fmaf(wr[5], ac[5], a);
        a = fmaf(wr[6], ac[6], a); a = fmaf(wr[7], ac[7], a);
        acc[r] = a;
      }
    }
    float vacc = 0.f;
    #pragma unroll
    for (int r = 0; r < RPW; ++r) vacc = fmaf(w_out[hb + r], acc[r], vacc);
    vpart[wid * SPB + lane] = vacc;
  }
  __syncthreads();   // P4 reads all of buf3; P4b writes slices of it

  // ---- P4b: g3 = (W3^T w_out) * (1 - A3^2), in place over A3 (buf3) ----
  {
    float* buf3 = smem + 3 * SPB * HID;
    const float* wp = w_h + 3 * HID * HID;
    float q[RPW] = {0.f, 0.f, 0.f, 0.f, 0.f, 0.f, 0.f, 0.f};
    #pragma unroll
    for (int c = 0; c < 16; ++c) {
      #pragma unroll
      for (int j = 0; j < 8; ++j) {
        const float g  = w_out[c * 8 + j];
        const float* wr = wp + (c * 8 + j) * HID + hb;
        q[0] = fmaf(wr[0], g, q[0]); q[1] = fmaf(wr[1], g, q[1]);
        q[2] = fmaf(wr[2], g, q[2]); q[3] = fmaf(wr[3], g, q[3]);
        q[4] = fmaf(wr[4], g, q[4]); q[5] = fmaf(wr[5], g, q[5]);
        q[6] = fmaf(wr[6], g, q[6]); q[7] = fmaf(wr[7], g, q[7]);
      }
    }
    float a8[8];
    load8(buf3, lane, wid, a8);              // own k-slice (granules 2w,2w+1)
    #pragma unroll
    for (int k = 0; k < 8; ++k) q[k] *= (1.f - a8[k] * a8[k]);
    store8(buf3, lane, wid, q);
  }
  __syncthreads();

  // ---- P5..P7: g_BL = (g_{BL+1}^T W_BL) * (1 - A_BL^2), in place ----
  for (int BL = 2; BL >= 0; --BL) {
    const float* gin  = smem + (BL + 1) * SPB * HID;
    float*       dbuf = smem + BL * SPB * HID;
    const float* wp   = w_h + BL * HID * HID;
    float q[RPW] = {0.f, 0.f, 0.f, 0.f, 0.f, 0.f, 0.f, 0.f};
    #pragma unroll
    for (int c = 0; c < 16; ++c) {
      float gc[8];
      load8(gin, lane, c, gc);
      #pragma unroll
      for (int j = 0; j < 8; ++j) {
        const float g  = gc[j];
        const float* wr = wp + (c * 8 + j) * HID + hb;  // 8 consecutive k
        q[0] = fmaf(wr[0], g, q[0]); q[1] = fmaf(wr[1], g, q[1]);
        q[2] = fmaf(wr[2], g, q[2]); q[3] = fmaf(wr[3], g, q[3]);
        q[4] = fmaf(wr[4], g, q[4]); q[5] = fmaf(wr[5], g, q[5]);
        q[6] = fmaf(wr[6], g, q[6]); q[7] = fmaf(wr[7], g, q[7]);
      }
    }
    float a8[8];
    load8(dbuf, lane, wid, a8);
    #pragma unroll
    for (int k = 0; k < 8; ++k) q[k] *= (1.f - a8[k] * a8[k]);
    store8(dbuf, lane, wid, q);
    __syncthreads();
  }

  // ---- P8: wave 0: V = sum(vpart)+b_out; J[n] = (g0^T w_in[:,n]) / r[n] ----
  if (wid == 0) {
    float v = b_out[0];
    #pragma unroll
    for (int w = 0; w < NW; ++w) v += vpart[w * SPB + lane];
    out[gs] = v;

    float J[N_DIMS] = {0.f, 0.f, 0.f, 0.f, 0.f, 0.f};
    #pragma unroll
    for (int c = 0; c < 16; ++c) {
      float g8[8];
      load8(smem, lane, c, g8);              // g0 lives in buf0
      #pragma unroll
      for (int j = 0; j < 8; ++j) {
        #pragma unroll
        for (int n = 0; n < N_DIMS; ++n)
          J[n] = fmaf(w_in[(c * 8 + j) * N_DIMS + n], g8[j], J[n]);
      }
    }
    float2* op = (float2*)(out + BS + gs * N_DIMS);
    op[0] = make_float2(J[0] / xr[0], J[1] / xr[1]);
    op[1] = make_float2(J[2] / xr[2], J[3] / xr[3]);
    op[2] = make_float2(J[4] / xr[4], J[5] / xr[5]);
  }
}

extern "C" void kernel_launch(void* const* d_in, const int* in_sizes, int n_in,
                              void* d_out, int out_size, void* d_ws, size_t ws_size,
                              hipStream_t stream) {
  const float* x     = (const float*)d_in[0];
  const float* xc    = (const float*)d_in[1];
  const float* xr    = (const float*)d_in[2];
  const float* w_in  = (const float*)d_in[3];
  const float* b_in  = (const float*)d_in[4];
  const float* w_h   = (const float*)d_in[5];
  const float* b_h   = (const float*)d_in[6];
  const float* w_out = (const float*)d_in[7];
  const float* b_out = (const float*)d_in[8];
  float* out = (float*)d_out;

  const size_t shmem = (size_t)(4 * SPB * HID + NW * SPB) * sizeof(float); // 135168 B
  (void)hipFuncSetAttribute((const void*)cbf_fused,
                            hipFuncAttributeMaxDynamicSharedMemorySize,
                            (int)shmem);
  cbf_fused<<<dim3(BS / SPB), dim3(NW * 64), shmem, stream>>>(
      x, xc, xr, w_in, b_in, w_h, b_h, w_out, b_out, out);
}

// Round 3
// 272.162 us; speedup vs baseline: 2.6996x; 1.2891x over previous
//
#include <hip/hip_runtime.h>

// SatelliteCBF V_with_jacobian, MI355X — round 3: bf16-split MFMA.
//
// VJP Jacobian (1-dim output): J = w_out*W3*D3*...*D0*W_in*diag(1/r).
// Layer-3 GEMM eliminated: u = W3^T w_out (setup), V = u.A3 + c, g3 = u*D3.
// Remaining 6 GEMMs (3 fwd, 3 bwd) run on v_mfma_f32_16x16x32_bf16 with
// two-term bf16 splits on BOTH operands (hi*hi + hi*lo + lo*hi, fp32 acc):
// dropped lo*lo ~ 2^-18 relative => fp32-grade accuracy at MFMA speed.
//
// Setup kernel (each call) writes into d_ws: bf16 splits of w_h[0..2] normal
// (Wa,Wb: A-operand rows = h) and transposed (WaT,WbT: rows = k'), plus
// u[128] and c = w_out.b3 + b_out.
//
// Main kernel: 64 samples/block, 16 waves. Activations A0..A3 as split bf16
// pairs in LDS [64][256B], XOR-swizzled 16B granules (T2): conflict-free
// b128 fragment reads. MFMA tiling: wave = (s-tile = wid&3) x (h-tile pair
// = (wid>>2)*2 +{0,1}); B-frags (activations) loaded once per layer, W-frags
// streamed from L2. Fragment k-permutation cancels between A and B operands;
// C/D layout col=lane&15, row=(lane>>4)*4+reg [guide-verified] drives all
// epilogue addressing (b64 quad writes). Backward overwrites A-buffers in
// place (disjoint (s,k')-quads per wave, barrier-separated).

#define N_DIMS 6
#define HID    128
#define BS     65536
#define SPB    64
#define NWAVES 16

typedef __attribute__((ext_vector_type(8))) short bf16x8;
typedef __attribute__((ext_vector_type(4))) short short4v;
typedef __attribute__((ext_vector_type(4))) float f32x4;

__device__ __forceinline__ float bf2f(short s) {
  unsigned u = ((unsigned)(unsigned short)s) << 16;
  return __builtin_bit_cast(float, u);
}
__device__ __forceinline__ short f2bf(float f) {   // RNE, finite inputs
  unsigned u = __builtin_bit_cast(unsigned, f);
  u += 0x7fffu + ((u >> 16) & 1u);
  return (short)(u >> 16);
}
__device__ __forceinline__ float fast_tanh(float x) {
  float e = __expf(2.0f * x);
  return 1.0f - 2.0f * __builtin_amdgcn_rcpf(e + 1.0f);
}
// swizzled byte offset in a [64][256B] LDS buffer (16B-granule XOR)
__device__ __forceinline__ int swb(int row, int col) {
  return row * 256 + ((col & ~15) ^ ((row & 7) << 4)) + (col & 15);
}

// ---------------- setup: weight splits + u,c into d_ws ----------------
__global__ void cbf_setup(const float* __restrict__ w_h,
                          const float* __restrict__ w_out,
                          const float* __restrict__ b_h,
                          const float* __restrict__ b_out,
                          short* __restrict__ Wa,  short* __restrict__ Wb,
                          short* __restrict__ WaT, short* __restrict__ WbT,
                          float* __restrict__ uc)
{
  const int idx = blockIdx.x * 256 + threadIdx.x;      // exactly 3*128*128
  {
    float w = w_h[idx];
    short a = f2bf(w);
    short b = f2bf(w - bf2f(a));
    const int L = idx >> 14, rc = idx & 16383, r = rc >> 7, c = rc & 127;
    Wa[idx] = a; Wb[idx] = b;
    const int t = (L << 14) + (c << 7) + r;            // transposed
    WaT[t] = a; WbT[t] = b;
  }
  if (blockIdx.x == 0) {
    const int t = threadIdx.x;
    if (t < 128) {                                     // u = W3^T w_out
      const float* w3 = w_h + 3 * 16384;
      float acc = 0.f;
      #pragma unroll 4
      for (int h = 0; h < 128; ++h)
        acc = fmaf(w_out[h], w3[h * 128 + t], acc);
      uc[t] = acc;
    } else if (t == 128) {                             // c = w_out.b3 + b_out
      float acc = b_out[0];
      for (int h = 0; h < 128; ++h)
        acc = fmaf(w_out[h], b_h[3 * 128 + h], acc);
      uc[128] = acc;
    }
  }
}

// ---------------- main fused kernel ----------------
__global__ __launch_bounds__(1024)
void cbf_main(const float* __restrict__ x,
              const float* __restrict__ xc,
              const float* __restrict__ xr,
              const float* __restrict__ w_in,
              const float* __restrict__ b_in,
              const float* __restrict__ b_h,
              const short* __restrict__ Wa,  const short* __restrict__ Wb,
              const short* __restrict__ WaT, const short* __restrict__ WbT,
              const float* __restrict__ uc,
              float* __restrict__ out)
{
  extern __shared__ char lds[];                 // 4 x (16KB hi + 16KB lo)
  float* vpart = (float*)(lds + 131072);        // [16][64]

  const int tid  = threadIdx.x;
  const int lane = tid & 63;
  const int wid  = __builtin_amdgcn_readfirstlane(tid >> 6);
  const int l15  = lane & 15;
  const int lg   = lane >> 4;                   // 0..3
  const int gs   = blockIdx.x * SPB + lane;

  const int stile = wid & 3;                    // wave's sample tile
  const int h2    = (wid >> 2) * 2;             // wave's h/k' tile pair base
  const int srow  = stile * 16 + l15;           // B-frag & C sample row

  // ---- P0: input layer (fp32 VALU, K=6), split-store A0 ----
  {
    float xn[N_DIMS];
    #pragma unroll
    for (int d = 0; d < N_DIMS; ++d)
      xn[d] = (x[gs * N_DIMS + d] - xc[d]) / xr[d];
    bf16x8 pa, pb;
    #pragma unroll
    for (int j = 0; j < 8; ++j) {
      const int h = wid * 8 + j;                // wave-uniform -> s_load w_in
      float a = b_in[h];
      #pragma unroll
      for (int d = 0; d < N_DIMS; ++d)
        a = fmaf(w_in[h * N_DIMS + d], xn[d], a);
      float t = fast_tanh(a);
      short hi = f2bf(t);
      pa[j] = hi;
      pb[j] = f2bf(t - bf2f(hi));
    }
    *(bf16x8*)(lds + swb(lane, wid * 16)) = pa;
    *(bf16x8*)(lds + 16384 + swb(lane, wid * 16)) = pb;
  }
  __syncthreads();

  // ---- P1..P3: forward hidden layers, MFMA ----
  for (int L = 0; L < 3; ++L) {
    const char* Xa = lds + L * 32768;
    const char* Xb = Xa + 16384;
    char* Ya = lds + (L + 1) * 32768;
    char* Yb = Ya + 16384;

    bf16x8 xa[4], xb[4];                        // B-frags: once per layer
    #pragma unroll
    for (int ch = 0; ch < 4; ++ch) {
      xa[ch] = *(const bf16x8*)(Xa + swb(srow, ch * 64 + lg * 16));
      xb[ch] = *(const bf16x8*)(Xb + swb(srow, ch * 64 + lg * 16));
    }
    #pragma unroll
    for (int ht = 0; ht < 2; ++ht) {
      const int htile = h2 + ht;
      const int wofs  = L * 16384 + (htile * 16 + l15) * 128 + lg * 8;
      f32x4 acc = {0.f, 0.f, 0.f, 0.f};
      #pragma unroll
      for (int ch = 0; ch < 4; ++ch) {
        bf16x8 wa = *(const bf16x8*)(Wa + wofs + ch * 32);
        bf16x8 wb = *(const bf16x8*)(Wb + wofs + ch * 32);
        acc = __builtin_amdgcn_mfma_f32_16x16x32_bf16(wa, xa[ch], acc, 0, 0, 0);
        acc = __builtin_amdgcn_mfma_f32_16x16x32_bf16(wa, xb[ch], acc, 0, 0, 0);
        acc = __builtin_amdgcn_mfma_f32_16x16x32_bf16(wb, xa[ch], acc, 0, 0, 0);
      }
      const float4 bias = *(const float4*)(b_h + L * HID + htile * 16 + lg * 4);
      short4v qa, qb;
      #pragma unroll
      for (int r = 0; r < 4; ++r) {
        float t = fast_tanh(acc[r] + ((const float*)&bias)[r]);
        short hi = f2bf(t);
        qa[r] = hi;
        qb[r] = f2bf(t - bf2f(hi));
      }
      *(short4v*)(Ya + swb(srow, htile * 32 + lg * 8)) = qa;
      *(short4v*)(Yb + swb(srow, htile * 32 + lg * 8)) = qb;
    }
    __syncthreads();
  }

  // ---- P4: V = u.A3 + c (partials) and g3 = u*(1-A3^2) in place ----
  {
    char* X3a = lds + 3 * 32768;
    char* X3b = X3a + 16384;
    float uu[8];
    #pragma unroll
    for (int j = 0; j < 8; ++j) uu[j] = uc[wid * 8 + j];   // uniform s_load
    bf16x8 ta = *(const bf16x8*)(X3a + swb(lane, wid * 16));
    bf16x8 tb = *(const bf16x8*)(X3b + swb(lane, wid * 16));
    float vp = 0.f;
    bf16x8 ga, gb;
    #pragma unroll
    for (int j = 0; j < 8; ++j) {
      float A = bf2f(ta[j]) + bf2f(tb[j]);
      vp = fmaf(uu[j], A, vp);
      float g = uu[j] * (1.f - A * A);
      short hi = f2bf(g);
      ga[j] = hi;
      gb[j] = f2bf(g - bf2f(hi));
    }
    vpart[wid * 64 + lane] = vp;
    *(bf16x8*)(X3a + swb(lane, wid * 16)) = ga;    // same wave slice: safe
    *(bf16x8*)(X3b + swb(lane, wid * 16)) = gb;
  }
  __syncthreads();

  if (tid < SPB) {
    float v = uc[128];
    #pragma unroll
    for (int w = 0; w < NWAVES; ++w) v += vpart[w * 64 + tid];
    out[blockIdx.x * SPB + tid] = v;
  }

  // ---- P5..P7: backward g_BL = (g_{BL+1}^T W_BL) * (1 - A_BL^2), MFMA ----
  for (int BL = 2; BL >= 0; --BL) {
    const char* Ga = lds + (BL + 1) * 32768;
    const char* Gb = Ga + 16384;
    char* Da = lds + BL * 32768;
    char* Db = Da + 16384;

    bf16x8 gfa[4], gfb[4];
    #pragma unroll
    for (int ch = 0; ch < 4; ++ch) {
      gfa[ch] = *(const bf16x8*)(Ga + swb(srow, ch * 64 + lg * 16));
      gfb[ch] = *(const bf16x8*)(Gb + swb(srow, ch * 64 + lg * 16));
    }
    #pragma unroll
    for (int kt = 0; kt < 2; ++kt) {
      const int ktile = h2 + kt;
      const int wofs  = BL * 16384 + (ktile * 16 + l15) * 128 + lg * 8;
      f32x4 acc = {0.f, 0.f, 0.f, 0.f};
      #pragma unroll
      for (int ch = 0; ch < 4; ++ch) {
        bf16x8 wa = *(const bf16x8*)(WaT + wofs + ch * 32);
        bf16x8 wb = *(const bf16x8*)(WbT + wofs + ch * 32);
        acc = __builtin_amdgcn_mfma_f32_16x16x32_bf16(wa, gfa[ch], acc, 0, 0, 0);
        acc = __builtin_amdgcn_mfma_f32_16x16x32_bf16(wa, gfb[ch], acc, 0, 0, 0);
        acc = __builtin_amdgcn_mfma_f32_16x16x32_bf16(wb, gfa[ch], acc, 0, 0, 0);
      }
      // D-scale from A_BL (read-then-overwrite own quads: in-place safe)
      short4v aq = *(short4v*)(Da + swb(srow, ktile * 32 + lg * 8));
      short4v bq = *(short4v*)(Db + swb(srow, ktile * 32 + lg * 8));
      short4v oa, ob;
      #pragma unroll
      for (int r = 0; r < 4; ++r) {
        float A = bf2f(aq[r]) + bf2f(bq[r]);
        float g = acc[r] * (1.f - A * A);
        short hi = f2bf(g);
        oa[r] = hi;
        ob[r] = f2bf(g - bf2f(hi));
      }
      *(short4v*)(Da + swb(srow, ktile * 32 + lg * 8)) = oa;
      *(short4v*)(Db + swb(srow, ktile * 32 + lg * 8)) = ob;
    }
    __syncthreads();
  }

  // ---- P8: J[n] = (g0^T w_in[:,n]) / r[n], k-sliced over waves ----
  {
    bf16x8 ja = *(const bf16x8*)(lds + swb(lane, wid * 16));
    bf16x8 jb = *(const bf16x8*)(lds + 16384 + swb(lane, wid * 16));
    float J[N_DIMS] = {0.f, 0.f, 0.f, 0.f, 0.f, 0.f};
    #pragma unroll
    for (int j = 0; j < 8; ++j) {
      float g = bf2f(ja[j]) + bf2f(jb[j]);
      const int k = wid * 8 + j;                 // uniform -> s_load w_in
      #pragma unroll
      for (int n = 0; n < N_DIMS; ++n)
        J[n] = fmaf(w_in[k * N_DIMS + n], g, J[n]);
    }
    float* Jp = (float*)(lds + 32768);           // buf1 dead: reuse
    #pragma unroll
    for (int n = 0; n < N_DIMS; ++n)
      Jp[(wid * 64 + lane) * N_DIMS + n] = J[n];
  }
  __syncthreads();
  if (tid < SPB * N_DIMS) {
    const float* Jp = (const float*)(lds + 32768);
    const int s = tid / N_DIMS, n = tid % N_DIMS;
    float a = 0.f;
    #pragma unroll
    for (int w = 0; w < NWAVES; ++w) a += Jp[(w * 64 + s) * N_DIMS + n];
    out[BS + (blockIdx.x * SPB + s) * N_DIMS + n] = a / xr[n];
  }
}

extern "C" void kernel_launch(void* const* d_in, const int* in_sizes, int n_in,
                              void* d_out, int out_size, void* d_ws, size_t ws_size,
                              hipStream_t stream) {
  const float* x     = (const float*)d_in[0];
  const float* xc    = (const float*)d_in[1];
  const float* xr    = (const float*)d_in[2];
  const float* w_in  = (const float*)d_in[3];
  const float* b_in  = (const float*)d_in[4];
  const float* w_h   = (const float*)d_in[5];
  const float* b_h   = (const float*)d_in[6];
  const float* w_out = (const float*)d_in[7];
  const float* b_out = (const float*)d_in[8];
  float* out = (float*)d_out;

  // d_ws layout: Wa|Wb|WaT|WbT (3*128*128 shorts each) | uc[129] f32  (~394KB)
  short* Wa  = (short*)d_ws;
  short* Wb  = Wa + 49152;
  short* WaT = Wb + 49152;
  short* WbT = WaT + 49152;
  float* uc  = (float*)(WbT + 49152);

  cbf_setup<<<dim3(192), dim3(256), 0, stream>>>(w_h, w_out, b_h, b_out,
                                                 Wa, Wb, WaT, WbT, uc);

  const size_t shmem = 4 * 32768 + NWAVES * SPB * sizeof(float);  // 135168 B
  (void)hipFuncSetAttribute((const void*)cbf_main,
                            hipFuncAttributeMaxDynamicSharedMemorySize,
                            (int)shmem);
  cbf_main<<<dim3(BS / SPB), dim3(1024), shmem, stream>>>(
      x, xc, xr, w_in, b_in, b_h, Wa, Wb, WaT, WbT, uc, out);
}

// Round 4
// 263.655 us; speedup vs baseline: 2.7867x; 1.0323x over previous
//
#include <hip/hip_runtime.h>

// SatelliteCBF V_with_jacobian, MI355X — round 4.
//
// Same bf16-split MFMA algorithm as R3 (VJP Jacobian, layer-3 GEMM folded
// into u = W3^T w_out; 6 GEMMs on v_mfma_f32_16x16x32_bf16 with two-term
// bf16 splits, fp32-grade accuracy). R3 was latency-bound: 132KB LDS -> 1
// block/CU -> barriers fully exposed (MfmaUtil 7.5%, VALUBusy 17%).
//
// R4 changes:
//  * SPB 64->32: LDS 66KB -> 2 blocks/CU (8 waves/SIMD); launch_bounds
//    (1024,8) caps VGPR at 64 (R3 used 40).
//  * Swizzle XOR (row&15) (was &7): 16 distinct granules per 16-lane phase
//    -> 2 req/bank = conflict-free (m136: 2-way is free).
//  * Setup kernel: LDS-tiled transpose (coalesced both sides, stride-129
//    u32 tile = conflict-free column reads) + parallel u-reduce. Was ~65us
//    of scatter stores + serial 128-iter chain; target <8us.
//
// Wave tiling (16 waves): stile = wid&1 (16-sample tile), htile = wid>>1
// (16-wide h/k' tile). C/D layout col=lane&15 (sample), row=(lane>>4)*4+reg
// (h) [guide m89]. A/B operand k-permutation cancels (symmetric layouts).

#define N_DIMS 6
#define HID    128
#define BS     65536
#define SPB    32
#define NWAVES 16

typedef __attribute__((ext_vector_type(8))) short bf16x8;
typedef __attribute__((ext_vector_type(4))) short short4v;
typedef __attribute__((ext_vector_type(4))) float f32x4;

__device__ __forceinline__ float bf2f(short s) {
  unsigned u = ((unsigned)(unsigned short)s) << 16;
  return __builtin_bit_cast(float, u);
}
__device__ __forceinline__ short f2bf(float f) {   // RNE, finite inputs
  unsigned u = __builtin_bit_cast(unsigned, f);
  u += 0x7fffu + ((u >> 16) & 1u);
  return (short)(u >> 16);
}
__device__ __forceinline__ float fast_tanh(float x) {
  float e = __expf(2.0f * x);
  return 1.0f - 2.0f * __builtin_amdgcn_rcpf(e + 1.0f);
}
// swizzled byte offset in a [32][256B] LDS buffer: XOR 16B granule with row&15
__device__ __forceinline__ int swb(int row, int col) {
  return row * 256 + ((col & ~15) ^ ((row & 15) << 4)) + (col & 15);
}

// ---------------- setup: weight splits (+transpose) + u,c ----------------
__global__ __launch_bounds__(1024)
void cbf_setup(const float* __restrict__ w_h,
               const float* __restrict__ w_out,
               const float* __restrict__ b_h,
               const float* __restrict__ b_out,
               short* __restrict__ Wa,  short* __restrict__ Wb,
               short* __restrict__ WaT, short* __restrict__ WbT,
               float* __restrict__ uc)
{
  const int tid = threadIdx.x;
  if (blockIdx.x < 3) {
    const int L = blockIdx.x;
    const float* W = w_h + L * 16384;
    __shared__ unsigned tile[64 * 129];          // hi<<16|lo, half-layer
    for (int half = 0; half < 2; ++half) {
      #pragma unroll
      for (int i = 0; i < 2; ++i) {
        const int p = half * 2048 + i * 1024 + tid;   // float4 index in layer
        const float4 w4 = *(const float4*)(W + p * 4);
        const float wv[4] = {w4.x, w4.y, w4.z, w4.w};
        short4v a, b;
        #pragma unroll
        for (int j = 0; j < 4; ++j) {
          const short hi = f2bf(wv[j]);
          a[j] = hi; b[j] = f2bf(wv[j] - bf2f(hi));
        }
        *(short4v*)(Wa + L * 16384 + p * 4) = a;
        *(short4v*)(Wb + L * 16384 + p * 4) = b;
        const int rl = ((p * 4) >> 7) - half * 64, c = (p * 4) & 127;
        #pragma unroll
        for (int j = 0; j < 4; ++j)
          tile[rl * 129 + c + j] =
              ((unsigned)(unsigned short)a[j] << 16) | (unsigned short)b[j];
      }
      __syncthreads();
      #pragma unroll
      for (int i = 0; i < 2; ++i) {
        const int q = i * 1024 + tid;            // quad over (c, r-group)
        const int c = q >> 4, rg = q & 15;
        short4v a, b;
        #pragma unroll
        for (int j = 0; j < 4; ++j) {
          const unsigned u = tile[(rg * 4 + j) * 129 + c];
          a[j] = (short)(u >> 16); b[j] = (short)(u & 0xffffu);
        }
        *(short4v*)(WaT + L * 16384 + c * 128 + half * 64 + rg * 4) = a;
        *(short4v*)(WbT + L * 16384 + c * 128 + half * 64 + rg * 4) = b;
      }
      __syncthreads();
    }
  } else {
    // u = W3^T w_out (8-way split reduce), c = w_out.b3 + b_out
    const float* w3 = w_h + 3 * 16384;
    __shared__ float ured[8][128];
    const int t = tid & 127, part = tid >> 7;
    float acc = 0.f;
    #pragma unroll
    for (int i = 0; i < 16; ++i) {
      const int h = part * 16 + i;
      acc = fmaf(w_out[h], w3[h * 128 + t], acc);
    }
    ured[part][t] = acc;
    __syncthreads();
    if (tid < 128) {
      float a = 0.f;
      #pragma unroll
      for (int p = 0; p < 8; ++p) a += ured[p][tid];
      uc[tid] = a;
    } else if (tid >= 128 && tid < 192) {
      const int l = tid - 128;
      float v = w_out[l] * b_h[3 * HID + l] + w_out[l + 64] * b_h[3 * HID + l + 64];
      v += __shfl_down(v, 32); v += __shfl_down(v, 16);
      v += __shfl_down(v, 8);  v += __shfl_down(v, 4);
      v += __shfl_down(v, 2);  v += __shfl_down(v, 1);
      if (l == 0) uc[128] = v + b_out[0];
    }
  }
}

// ---------------- main fused kernel ----------------
__global__ __launch_bounds__(1024, 8)
void cbf_main(const float* __restrict__ x,
              const float* __restrict__ xc,
              const float* __restrict__ xr,
              const float* __restrict__ w_in,
              const float* __restrict__ b_in,
              const float* __restrict__ b_h,
              const short* __restrict__ Wa,  const short* __restrict__ Wb,
              const short* __restrict__ WaT, const short* __restrict__ WbT,
              const float* __restrict__ uc,
              float* __restrict__ out)
{
  extern __shared__ char lds[];               // 4 x (8KB hi + 8KB lo) = 64KB
  float* vpart = (float*)(lds + 65536);       // [16][32]

  const int tid  = threadIdx.x;
  const int lane = tid & 63;
  const int wid  = __builtin_amdgcn_readfirstlane(tid >> 6);
  const int l15  = lane & 15;
  const int lg   = lane >> 4;                 // 0..3
  const int s    = lane & 31;                 // sample row (P0/P4/P8)
  const int half = lane >> 5;                 // 0/1

  const int stile = wid & 1;
  const int htile = wid >> 1;                 // 0..7
  const int srow  = stile * 16 + l15;         // sample row for MFMA frags

  // ---- P0: input layer (fp32 VALU, K=6), split-store A0 ----
  {
    const int gs = blockIdx.x * SPB + s;
    float xn[N_DIMS];
    const float2* xp = (const float2*)(x + gs * N_DIMS);
    const float2 x0 = xp[0], x1 = xp[1], x2 = xp[2];
    xn[0] = (x0.x - xc[0]) / xr[0];
    xn[1] = (x0.y - xc[1]) / xr[1];
    xn[2] = (x1.x - xc[2]) / xr[2];
    xn[3] = (x1.y - xc[3]) / xr[3];
    xn[4] = (x2.x - xc[4]) / xr[4];
    xn[5] = (x2.y - xc[5]) / xr[5];
    short4v pa, pb;
    #pragma unroll
    for (int j = 0; j < 4; ++j) {
      const int h = wid * 8 + half * 4 + j;
      float a = b_in[h];
      #pragma unroll
      for (int d = 0; d < N_DIMS; ++d)
        a = fmaf(w_in[h * N_DIMS + d], xn[d], a);
      const float t = fast_tanh(a);
      const short hi = f2bf(t);
      pa[j] = hi; pb[j] = f2bf(t - bf2f(hi));
    }
    const int off = swb(s, wid * 16 + half * 8);
    *(short4v*)(lds + off) = pa;
    *(short4v*)(lds + 8192 + off) = pb;
  }
  __syncthreads();

  // ---- P1..P3: forward hidden layers, MFMA ----
  for (int L = 0; L < 3; ++L) {
    const char* Xa = lds + L * 16384;
    const char* Xb = Xa + 8192;
    char* Ya = lds + (L + 1) * 16384;
    char* Yb = Ya + 8192;
    const int wbase = L * 16384 + (htile * 16 + l15) * 128 + lg * 8;
    f32x4 acc = {0.f, 0.f, 0.f, 0.f};
    #pragma unroll
    for (int ch = 0; ch < 4; ++ch) {
      const int boff = swb(srow, ch * 64 + lg * 16);
      const bf16x8 xa = *(const bf16x8*)(Xa + boff);
      const bf16x8 xb = *(const bf16x8*)(Xb + boff);
      const bf16x8 wa = *(const bf16x8*)(Wa + wbase + ch * 32);
      const bf16x8 wb = *(const bf16x8*)(Wb + wbase + ch * 32);
      acc = __builtin_amdgcn_mfma_f32_16x16x32_bf16(wa, xa, acc, 0, 0, 0);
      acc = __builtin_amdgcn_mfma_f32_16x16x32_bf16(wa, xb, acc, 0, 0, 0);
      acc = __builtin_amdgcn_mfma_f32_16x16x32_bf16(wb, xa, acc, 0, 0, 0);
    }
    const float4 bias = *(const float4*)(b_h + L * HID + htile * 16 + lg * 4);
    short4v qa, qb;
    #pragma unroll
    for (int r = 0; r < 4; ++r) {
      const float t = fast_tanh(acc[r] + ((const float*)&bias)[r]);
      const short hi = f2bf(t);
      qa[r] = hi; qb[r] = f2bf(t - bf2f(hi));
    }
    const int ooff = swb(srow, htile * 32 + lg * 8);
    *(short4v*)(Ya + ooff) = qa;
    *(short4v*)(Yb + ooff) = qb;
    __syncthreads();
  }

  // ---- P4: V partials (u.A3 + c) and g3 = u*(1-A3^2) in place ----
  {
    char* X3a = lds + 3 * 16384;
    char* X3b = X3a + 8192;
    const int off = swb(s, wid * 16 + half * 8);
    const short4v ta = *(const short4v*)(X3a + off);
    const short4v tb = *(const short4v*)(X3b + off);
    float vp = 0.f;
    short4v ga, gb;
    #pragma unroll
    for (int j = 0; j < 4; ++j) {
      const float uj = uc[wid * 8 + half * 4 + j];
      const float A = bf2f(ta[j]) + bf2f(tb[j]);
      vp = fmaf(uj, A, vp);
      const float g = uj * (1.f - A * A);
      const short hi = f2bf(g);
      ga[j] = hi; gb[j] = f2bf(g - bf2f(hi));
    }
    *(short4v*)(X3a + off) = ga;
    *(short4v*)(X3b + off) = gb;
    vp += __shfl_down(vp, 32);
    if (lane < 32) vpart[wid * 32 + s] = vp;
  }
  __syncthreads();

  if (tid < SPB) {
    float v = uc[128];
    #pragma unroll
    for (int w = 0; w < NWAVES; ++w) v += vpart[w * 32 + tid];
    out[blockIdx.x * SPB + tid] = v;
  }

  // ---- P5..P7: backward g_BL = (g_{BL+1}^T W_BL) * (1 - A_BL^2), MFMA ----
  for (int BL = 2; BL >= 0; --BL) {
    const char* Ga = lds + (BL + 1) * 16384;
    const char* Gb = Ga + 8192;
    char* Da = lds + BL * 16384;
    char* Db = Da + 8192;
    const int wbase = BL * 16384 + (htile * 16 + l15) * 128 + lg * 8;
    f32x4 acc = {0.f, 0.f, 0.f, 0.f};
    #pragma unroll
    for (int ch = 0; ch < 4; ++ch) {
      const int boff = swb(srow, ch * 64 + lg * 16);
      const bf16x8 ga = *(const bf16x8*)(Ga + boff);
      const bf16x8 gb = *(const bf16x8*)(Gb + boff);
      const bf16x8 wa = *(const bf16x8*)(WaT + wbase + ch * 32);
      const bf16x8 wb = *(const bf16x8*)(WbT + wbase + ch * 32);
      acc = __builtin_amdgcn_mfma_f32_16x16x32_bf16(wa, ga, acc, 0, 0, 0);
      acc = __builtin_amdgcn_mfma_f32_16x16x32_bf16(wa, gb, acc, 0, 0, 0);
      acc = __builtin_amdgcn_mfma_f32_16x16x32_bf16(wb, ga, acc, 0, 0, 0);
    }
    const int doff = swb(srow, htile * 32 + lg * 8);
    const short4v aq = *(const short4v*)(Da + doff);
    const short4v bq = *(const short4v*)(Db + doff);
    short4v oa, ob;
    #pragma unroll
    for (int r = 0; r < 4; ++r) {
      const float A = bf2f(aq[r]) + bf2f(bq[r]);
      const float g = acc[r] * (1.f - A * A);
      const short hi = f2bf(g);
      oa[r] = hi; ob[r] = f2bf(g - bf2f(hi));
    }
    *(short4v*)(Da + doff) = oa;
    *(short4v*)(Db + doff) = ob;
    __syncthreads();
  }

  // ---- P8: J[n] = (g0^T w_in[:,n]) / r[n] ----
  {
    const int off = swb(s, wid * 16 + half * 8);
    const short4v ja = *(const short4v*)(lds + off);
    const short4v jb = *(const short4v*)(lds + 8192 + off);
    float J[N_DIMS] = {0.f, 0.f, 0.f, 0.f, 0.f, 0.f};
    #pragma unroll
    for (int j = 0; j < 4; ++j) {
      const float g = bf2f(ja[j]) + bf2f(jb[j]);
      const int k = wid * 8 + half * 4 + j;
      #pragma unroll
      for (int n = 0; n < N_DIMS; ++n)
        J[n] = fmaf(w_in[k * N_DIMS + n], g, J[n]);
    }
    #pragma unroll
    for (int n = 0; n < N_DIMS; ++n) J[n] += __shfl_down(J[n], 32);
    if (lane < 32) {
      float* Jp = (float*)(lds + 16384);        // buf1 dead: reuse
      #pragma unroll
      for (int n = 0; n < N_DIMS; ++n)
        Jp[(wid * 32 + s) * N_DIMS + n] = J[n];
    }
  }
  __syncthreads();
  if (tid < SPB * N_DIMS) {
    const float* Jp = (const float*)(lds + 16384);
    const int ss = tid / N_DIMS, n = tid % N_DIMS;
    float a = 0.f;
    #pragma unroll
    for (int w = 0; w < NWAVES; ++w) a += Jp[(w * 32 + ss) * N_DIMS + n];
    out[BS + (blockIdx.x * SPB + ss) * N_DIMS + n] = a / xr[n];
  }
}

extern "C" void kernel_launch(void* const* d_in, const int* in_sizes, int n_in,
                              void* d_out, int out_size, void* d_ws, size_t ws_size,
                              hipStream_t stream) {
  const float* x     = (const float*)d_in[0];
  const float* xc    = (const float*)d_in[1];
  const float* xr    = (const float*)d_in[2];
  const float* w_in  = (const float*)d_in[3];
  const float* b_in  = (const float*)d_in[4];
  const float* w_h   = (const float*)d_in[5];
  const float* b_h   = (const float*)d_in[6];
  const float* w_out = (const float*)d_in[7];
  const float* b_out = (const float*)d_in[8];
  float* out = (float*)d_out;

  // d_ws: Wa|Wb|WaT|WbT (3*128*128 shorts each) | uc[129] f32
  short* Wa  = (short*)d_ws;
  short* Wb  = Wa + 49152;
  short* WaT = Wb + 49152;
  short* WbT = WaT + 49152;
  float* uc  = (float*)(WbT + 49152);

  cbf_setup<<<dim3(4), dim3(1024), 0, stream>>>(w_h, w_out, b_h, b_out,
                                                Wa, Wb, WaT, WbT, uc);

  const size_t shmem = 65536 + NWAVES * SPB * sizeof(float);   // 67584 B
  (void)hipFuncSetAttribute((const void*)cbf_main,
                            hipFuncAttributeMaxDynamicSharedMemorySize,
                            (int)shmem);
  cbf_main<<<dim3(BS / SPB), dim3(1024), shmem, stream>>>(
      x, xc, xr, w_in, b_in, b_h, Wa, Wb, WaT, WbT, uc, out);
}

// Round 5
// 163.393 us; speedup vs baseline: 4.4967x; 1.6136x over previous
//
#include <hip/hip_runtime.h>

// SatelliteCBF V_with_jacobian, MI355X — round 5: per-wave-full-layer,
// register-resident activations, zero-barrier act exchange.
//
// R4 lesson: lockstep micro-phases are latency-bound regardless of occupancy
// (207us at 46% occ == 208us at 85% occ). This round each wave owns ALL 128
// h/k' rows of a layer for its 16 samples: 96 MFMA + ~400 VALU of independent
// work per phase, no cross-wave activation traffic.
//
// - MFMA C/D (m89): n = lane&15, h = (lane>>4)*4+reg. A/B frag slot (lg,j)
//   <-> element k = ch*32+lg*8+j (validated by R3/R4 passing).
// - D->B-frag conversion via wave-PRIVATE LDS roundtrip (packed u32 [hi|lo]
//   per element, 16B-granule XOR swizzle g^=(row<<1)&31 -> 2-way = free).
//   No __syncthreads: same-wave DS ops are ordered.
// - Weights pre-split (bf16 hi+lo) AND pre-arranged in A-fragment order by
//   the setup kernel -> staging is a linear 16B/lane copy; weight ds_reads
//   are lane-contiguous (conflict-free). 8 stages: Win(16K), W0,W1,W2(64K),
//   W2T,W1T,W0T(64K), WinT(8K). Stage s prefetched to regs at phase s-1
//   start (hidden under compute), ds_written between 2 barriers.
// - D-factors (1-A^2) persist in f32 regs (exact): D0,D1,D2 = 96 VGPR.
// - V = u.A3 + c (u = W3^T w_out from setup); J via WinT MFMA (rows = dim).

#define N_DIMS 6
#define HID    128
#define BS     65536

typedef __attribute__((ext_vector_type(8))) short bf16x8;
typedef __attribute__((ext_vector_type(4))) float f32x4;

// d_ws byte offsets (total 418308 B)
#define SB0   0        // Win K32-pad  [Wa 8K | Wb 8K]
#define SB1   16384    // W0  fwd      [Wa 32K | Wb 32K]
#define SB2   81920    // W1  fwd
#define SB3   147456   // W2  fwd
#define SB4   212992   // W2T
#define SB5   278528   // W1T
#define SB6   344064   // W0T
#define SB7   409600   // WinT pad     [Wa 4K | Wb 4K]
#define UCOFF 417792   // u[128] f32, c at [128]

__device__ __forceinline__ float fast_tanh(float x) {
  float e = __expf(2.0f * x);
  return 1.0f - 2.0f * __builtin_amdgcn_rcpf(e + 1.0f);
}
// f32 -> packed u32 [bf16hi | bf16lo], both RNE; hi+lo ~= t to 2^-17 rel
__device__ __forceinline__ unsigned packsplit(float t) {
  unsigned u = __builtin_bit_cast(unsigned, t);
  unsigned hi = (u + 0x7fffu + ((u >> 16) & 1u)) & 0xffff0000u;
  float lo = t - __builtin_bit_cast(float, hi);
  unsigned ul = __builtin_bit_cast(unsigned, lo);
  unsigned lob = (ul + 0x7fffu + ((ul >> 16) & 1u)) >> 16;
  return hi | lob;
}

__device__ __forceinline__ void mfma3(f32x4& acc, bf16x8 wa, bf16x8 wb,
                                      bf16x8 xa, bf16x8 xb) {
  acc = __builtin_amdgcn_mfma_f32_16x16x32_bf16(wa, xa, acc, 0, 0, 0);
  acc = __builtin_amdgcn_mfma_f32_16x16x32_bf16(wa, xb, acc, 0, 0, 0);
  acc = __builtin_amdgcn_mfma_f32_16x16x32_bf16(wb, xa, acc, 0, 0, 0);
}

// ---------------- setup: fragment-order weight images + u,c ----------------
__global__ __launch_bounds__(1024)
void cbf_setup(const float* __restrict__ w_h, const float* __restrict__ w_in,
               const float* __restrict__ w_out, const float* __restrict__ b_h,
               const float* __restrict__ b_out, char* __restrict__ ws)
{
  const int tid = threadIdx.x, blk = blockIdx.x;
  if (blk < 48) {                       // w_h fwd + transposed images
    const int e = blk * 1024 + tid;     // 3*128*128
    const int L = e >> 14, rc = e & 16383, r = rc >> 7, c = rc & 127;
    const unsigned pk = packsplit(w_h[e]);
    const short hi = (short)(pk >> 16), lo = (short)(pk & 0xffffu);
    {  // fwd: A-rows = r(h), K = c
      short* Wa = (short*)(ws + SB1 + L * 65536);
      const int idx = (((r >> 4) * 4 + (c >> 5)) * 64 +
                       ((c >> 3) & 3) * 16 + (r & 15)) * 8 + (c & 7);
      Wa[idx] = hi; Wa[idx + 16384] = lo;
    }
    {  // bwd T: A-rows = c(k'), K = r
      short* Wa = (short*)(ws + SB6 - L * 65536);
      const int idx = (((c >> 4) * 4 + (r >> 5)) * 64 +
                       ((r >> 3) & 3) * 16 + (c & 15)) * 8 + (r & 7);
      Wa[idx] = hi; Wa[idx + 16384] = lo;
    }
  } else if (blk < 52) {                // Win K32-pad: rows h, K = k (6 real)
    const int e = (blk - 48) * 1024 + tid;     // 128*32
    const int r = e >> 5, c = e & 31;
    const unsigned pk = packsplit((c < 6) ? w_in[r * 6 + c] : 0.f);
    short* Wa = (short*)(ws + SB0);
    const int idx = ((r >> 4) * 64 + ((c >> 3) & 3) * 16 + (r & 15)) * 8 + (c & 7);
    Wa[idx] = (short)(pk >> 16); Wa[idx + 4096] = (short)(pk & 0xffffu);
  } else if (blk < 54) {                // WinT pad: rows d (6 real), K = k
    const int e = (blk - 52) * 1024 + tid;     // 16*128
    const int k = e >> 4, d = e & 15;
    const unsigned pk = packsplit((d < 6) ? w_in[k * 6 + d] : 0.f);
    short* Wa = (short*)(ws + SB7);
    const int idx = ((k >> 5) * 64 + ((k >> 3) & 3) * 16 + d) * 8 + (k & 7);
    Wa[idx] = (short)(pk >> 16); Wa[idx + 2048] = (short)(pk & 0xffffu);
  } else {                              // u = W3^T w_out, c = w_out.b3+b_out
    float* ucp = (float*)(ws + UCOFF);
    const float* w3 = w_h + 3 * 16384;
    __shared__ float ured[8][128];
    const int t = tid & 127, part = tid >> 7;
    float acc = 0.f;
    #pragma unroll
    for (int i = 0; i < 16; ++i) {
      const int h = part * 16 + i;
      acc = fmaf(w_out[h], w3[h * 128 + t], acc);
    }
    ured[part][t] = acc;
    __syncthreads();
    if (tid < 128) {
      float a = 0.f;
      #pragma unroll
      for (int p = 0; p < 8; ++p) a += ured[p][tid];
      ucp[tid] = a;
    } else if (tid < 192) {
      const int l = tid - 128;
      float v = w_out[l] * b_h[3 * HID + l] + w_out[l + 64] * b_h[3 * HID + l + 64];
      v += __shfl_down(v, 32); v += __shfl_down(v, 16); v += __shfl_down(v, 8);
      v += __shfl_down(v, 4);  v += __shfl_down(v, 2);  v += __shfl_down(v, 1);
      if (l == 0) ucp[128] = v + b_out[0];
    }
  }
}

// ---------------- main kernel helpers ----------------
template<int CNT>
__device__ __forceinline__ void pf_load(const char* ws, int sbase, int tid, float4* pf) {
  const float4* s = (const float4*)(ws + sbase);
  #pragma unroll
  for (int k = 0; k < CNT; ++k) pf[k] = s[k * 512 + tid];
}
template<int CNT>
__device__ __forceinline__ void st_write(char* Wbuf, int tid, const float4* pf) {
  #pragma unroll
  for (int k = 0; k < CNT; ++k) *(float4*)(Wbuf + (k * 512 + tid) * 16) = pf[k];
}

// full 128-wide layer: 8 h-tiles x 4 chunks x 3 split-terms
__device__ __forceinline__ void layer128(const char* Wbuf, int lane,
                                         const bf16x8* xa, const bf16x8* xb,
                                         f32x4* acc) {
  #pragma unroll
  for (int ht = 0; ht < 8; ++ht) {
    acc[ht] = (f32x4){0.f, 0.f, 0.f, 0.f};
    #pragma unroll
    for (int ch = 0; ch < 4; ++ch) {
      const bf16x8 wa = *(const bf16x8*)(Wbuf + (ht * 4 + ch) * 1024 + lane * 16);
      const bf16x8 wb = *(const bf16x8*)(Wbuf + 32768 + (ht * 4 + ch) * 1024 + lane * 16);
      mfma3(acc[ht], wa, wb, xa[ch], xb[ch]);
    }
  }
}

// read back B-frags from the wave-private act buffer (packed u32 elements)
__device__ __forceinline__ void rt_read(const char* act, int l15, int lg,
                                        bf16x8* xa, bf16x8* xb) {
  const int m = (l15 << 1) & 31;
  #pragma unroll
  for (int ch = 0; ch < 4; ++ch) {
    const int g0 = (ch * 8 + lg * 2) ^ m;
    const uint4 q0 = *(const uint4*)(act + (l15 * 32 + g0) * 16);
    const uint4 q1 = *(const uint4*)(act + (l15 * 32 + (g0 | 1)) * 16);
    uint4 A, B;
    A.x = __builtin_amdgcn_perm(q0.y, q0.x, 0x07060302u);
    A.y = __builtin_amdgcn_perm(q0.w, q0.z, 0x07060302u);
    A.z = __builtin_amdgcn_perm(q1.y, q1.x, 0x07060302u);
    A.w = __builtin_amdgcn_perm(q1.w, q1.z, 0x07060302u);
    B.x = __builtin_amdgcn_perm(q0.y, q0.x, 0x05040100u);
    B.y = __builtin_amdgcn_perm(q0.w, q0.z, 0x05040100u);
    B.z = __builtin_amdgcn_perm(q1.y, q1.x, 0x05040100u);
    B.w = __builtin_amdgcn_perm(q1.w, q1.z, 0x05040100u);
    xa[ch] = __builtin_bit_cast(bf16x8, A);
    xb[ch] = __builtin_bit_cast(bf16x8, B);
  }
}

__device__ __forceinline__ void rt_write_tile(char* act, int l15, int lg, int ht,
                                              unsigned q0, unsigned q1,
                                              unsigned q2, unsigned q3) {
  const int m = (l15 << 1) & 31;
  *(uint4*)(act + (l15 * 32 + ((ht * 4 + lg) ^ m)) * 16) = (uint4){q0, q1, q2, q3};
}

// ---------------- main fused kernel ----------------
__global__ __launch_bounds__(512, 2)
void cbf_main(const float* __restrict__ x, const float* __restrict__ xc,
              const float* __restrict__ xr, const float* __restrict__ b_in,
              const float* __restrict__ b_h, const char* __restrict__ ws,
              float* __restrict__ out)
{
  extern __shared__ char lds[];               // [64K weights][8 x 8K act]
  const int tid  = threadIdx.x;
  const int lane = tid & 63;
  const int wid  = __builtin_amdgcn_readfirstlane(tid >> 6);
  const int l15  = lane & 15;
  const int lg   = lane >> 4;
  const int gsmp = blockIdx.x * 128 + wid * 16 + l15;

  char* Wbuf = lds;
  char* act  = lds + 65536 + wid * 8192;
  const float* uc = (const float*)(ws + UCOFF);
  const float cval = uc[128];

  float4 pf[8];
  // stage 0 (Win image, 16K)
  pf_load<2>(ws, SB0, tid, pf);
  st_write<2>(Wbuf, tid, pf);
  __syncthreads();

  bf16x8 fa[4], fb[4];
  f32x4 acc[8];
  float D0_[32], D1_[32], D2_[32];

  // ---- phase 0: Win (K=32 padded, 1 chunk) -> A0, D0 ----
  pf_load<8>(ws, SB1, tid, pf);
  {
    float xn[6];
    #pragma unroll
    for (int d = 0; d < 6; ++d)
      xn[d] = (x[gsmp * 6 + d] - xc[d]) / xr[d];
    unsigned p[8];
    #pragma unroll
    for (int j = 0; j < 8; ++j) {
      unsigned v = (j < 6) ? packsplit(xn[j < 6 ? j : 0]) : 0u;
      p[j] = (lg == 0) ? v : 0u;
    }
    uint4 A, B;
    A.x = __builtin_amdgcn_perm(p[1], p[0], 0x07060302u);
    A.y = __builtin_amdgcn_perm(p[3], p[2], 0x07060302u);
    A.z = __builtin_amdgcn_perm(p[5], p[4], 0x07060302u);
    A.w = 0u;
    B.x = __builtin_amdgcn_perm(p[1], p[0], 0x05040100u);
    B.y = __builtin_amdgcn_perm(p[3], p[2], 0x05040100u);
    B.z = __builtin_amdgcn_perm(p[5], p[4], 0x05040100u);
    B.w = 0u;
    const bf16x8 xna = __builtin_bit_cast(bf16x8, A);
    const bf16x8 xnb = __builtin_bit_cast(bf16x8, B);
    #pragma unroll
    for (int ht = 0; ht < 8; ++ht) {
      acc[ht] = (f32x4){0.f, 0.f, 0.f, 0.f};
      const bf16x8 wa = *(const bf16x8*)(Wbuf + ht * 1024 + lane * 16);
      const bf16x8 wb = *(const bf16x8*)(Wbuf + 8192 + ht * 1024 + lane * 16);
      mfma3(acc[ht], wa, wb, xna, xnb);
    }
    #pragma unroll
    for (int ht = 0; ht < 8; ++ht) {
      const float4 b4 = *(const float4*)(b_in + ht * 16 + lg * 4);
      unsigned q[4];
      #pragma unroll
      for (int r = 0; r < 4; ++r) {
        const float t = fast_tanh(acc[ht][r] + ((const float*)&b4)[r]);
        D0_[ht * 4 + r] = fmaf(-t, t, 1.0f);
        q[r] = packsplit(t);
      }
      rt_write_tile(act, l15, lg, ht, q[0], q[1], q[2], q[3]);
    }
    rt_read(act, l15, lg, fa, fb);
  }
  __syncthreads();
  st_write<8>(Wbuf, tid, pf);
  __syncthreads();

  // ---- phases 1,2: W0 -> A1,D1 ; W1 -> A2,D2 ----
  #define FWD_PHASE(SBNEXT, BIAS, DARR)                                        \
  {                                                                            \
    pf_load<8>(ws, SBNEXT, tid, pf);                                           \
    layer128(Wbuf, lane, fa, fb, acc);                                         \
    _Pragma("unroll")                                                          \
    for (int ht = 0; ht < 8; ++ht) {                                           \
      const float4 b4 = *(const float4*)((BIAS) + ht * 16 + lg * 4);           \
      unsigned q[4];                                                           \
      _Pragma("unroll")                                                        \
      for (int r = 0; r < 4; ++r) {                                            \
        const float t = fast_tanh(acc[ht][r] + ((const float*)&b4)[r]);        \
        DARR[ht * 4 + r] = fmaf(-t, t, 1.0f);                                  \
        q[r] = packsplit(t);                                                   \
      }                                                                        \
      rt_write_tile(act, l15, lg, ht, q[0], q[1], q[2], q[3]);                 \
    }                                                                          \
    rt_read(act, l15, lg, fa, fb);                                             \
    __syncthreads();                                                           \
    st_write<8>(Wbuf, tid, pf);                                                \
    __syncthreads();                                                           \
  }
  FWD_PHASE(SB2, b_h, D1_)
  FWD_PHASE(SB3, b_h + HID, D2_)

  // ---- phase 3: W2 -> A3; V = u.A3 + c; g3 = u*(1-A3^2) ----
  {
    pf_load<8>(ws, SB4, tid, pf);
    layer128(Wbuf, lane, fa, fb, acc);
    float vp = 0.f;
    #pragma unroll
    for (int ht = 0; ht < 8; ++ht) {
      const float4 b4 = *(const float4*)(b_h + 2 * HID + ht * 16 + lg * 4);
      const float4 u4 = *(const float4*)(uc + ht * 16 + lg * 4);
      unsigned q[4];
      #pragma unroll
      for (int r = 0; r < 4; ++r) {
        const float t = fast_tanh(acc[ht][r] + ((const float*)&b4)[r]);
        const float uu = ((const float*)&u4)[r];
        vp = fmaf(uu, t, vp);
        q[r] = packsplit(uu * fmaf(-t, t, 1.0f));
      }
      rt_write_tile(act, l15, lg, ht, q[0], q[1], q[2], q[3]);
    }
    vp += __shfl_xor(vp, 16);
    vp += __shfl_xor(vp, 32);
    if (lg == 0) out[gsmp] = vp + cval;
    rt_read(act, l15, lg, fa, fb);
    __syncthreads();
    st_write<8>(Wbuf, tid, pf);
    __syncthreads();
  }

  // ---- phases 4,5,6: g2 = D2*(W2T g3); g1 = D1*(W1T g2); g0 = D0*(W0T g1) ----
  #define BWD_PHASE(SBNEXT, PFCNT, DARR)                                       \
  {                                                                            \
    pf_load<PFCNT>(ws, SBNEXT, tid, pf);                                       \
    layer128(Wbuf, lane, fa, fb, acc);                                         \
    _Pragma("unroll")                                                          \
    for (int ht = 0; ht < 8; ++ht) {                                           \
      unsigned q[4];                                                           \
      _Pragma("unroll")                                                        \
      for (int r = 0; r < 4; ++r)                                              \
        q[r] = packsplit(acc[ht][r] * DARR[ht * 4 + r]);                       \
      rt_write_tile(act, l15, lg, ht, q[0], q[1], q[2], q[3]);                 \
    }                                                                          \
    rt_read(act, l15, lg, fa, fb);                                             \
    __syncthreads();                                                           \
    st_write<PFCNT>(Wbuf, tid, pf);                                            \
    __syncthreads();                                                           \
  }
  BWD_PHASE(SB5, 8, D2_)
  BWD_PHASE(SB6, 8, D1_)
  BWD_PHASE(SB7, 1, D0_)

  // ---- phase 7: WinT -> J rows = dim (0..5 valid) ----
  {
    f32x4 aj = (f32x4){0.f, 0.f, 0.f, 0.f};
    #pragma unroll
    for (int ch = 0; ch < 4; ++ch) {
      const bf16x8 wa = *(const bf16x8*)(Wbuf + ch * 1024 + lane * 16);
      const bf16x8 wb = *(const bf16x8*)(Wbuf + 4096 + ch * 1024 + lane * 16);
      mfma3(aj, wa, wb, fa[ch], fb[ch]);
    }
    #pragma unroll
    for (int r = 0; r < 4; ++r) {
      const int d = lg * 4 + r;
      if (d < 6) out[BS + gsmp * 6 + d] = aj[r] / xr[d];
    }
  }
}

extern "C" void kernel_launch(void* const* d_in, const int* in_sizes, int n_in,
                              void* d_out, int out_size, void* d_ws, size_t ws_size,
                              hipStream_t stream) {
  const float* x     = (const float*)d_in[0];
  const float* xc    = (const float*)d_in[1];
  const float* xr    = (const float*)d_in[2];
  const float* w_in  = (const float*)d_in[3];
  const float* b_in  = (const float*)d_in[4];
  const float* w_h   = (const float*)d_in[5];
  const float* b_h   = (const float*)d_in[6];
  const float* w_out = (const float*)d_in[7];
  const float* b_out = (const float*)d_in[8];
  float* out = (float*)d_out;
  char* ws   = (char*)d_ws;

  cbf_setup<<<dim3(55), dim3(1024), 0, stream>>>(w_h, w_in, w_out, b_h, b_out, ws);

  const size_t shmem = 65536 + 8 * 8192;      // 131072 B
  (void)hipFuncSetAttribute((const void*)cbf_main,
                            hipFuncAttributeMaxDynamicSharedMemorySize,
                            (int)shmem);
  cbf_main<<<dim3(BS / 128), dim3(512), shmem, stream>>>(
      x, xc, xr, b_in, b_h, ws, out);
}